// Round 7
// baseline (672.173 us; speedup 1.0000x reference)
//
#include <hip/hip_runtime.h>

// ---------------- types & helpers ----------------
typedef __attribute__((ext_vector_type(4))) float  f32x4;
typedef __attribute__((ext_vector_type(8))) short  s16x8;

__device__ __forceinline__ short f2bf(float f) {
    unsigned u = __builtin_bit_cast(unsigned, f);
    u += 0x7FFFu + ((u >> 16) & 1u);            // round-to-nearest-even
    return (short)(u >> 16);
}
__device__ __forceinline__ float bf2f(short s) {
    unsigned u = ((unsigned)(unsigned short)s) << 16;
    return __builtin_bit_cast(float, u);
}

#define DEPTH 128   // D == H*C == 128
#define HEADS 8
#define TILE_M 64
#define SEGCAP 16

// ---------------- kernel 0: W -> bf16, transposed (Wt[c][k]) ----------------
// order: 0=Wq 1=Wk 2=Wv 3=We 4=Wskip
__global__ void prep_w(const float* __restrict__ Wq, const float* __restrict__ Wk,
                       const float* __restrict__ Wv, const float* __restrict__ We,
                       const float* __restrict__ Wsk, short* __restrict__ Wt5) {
    int idx = blockIdx.x * 256 + threadIdx.x;
    if (idx >= 5 * DEPTH * DEPTH) return;
    int mat = idx >> 14;
    int rem = idx & 16383;
    int k = rem >> 7, c = rem & 127;
    const float* W = (mat == 0) ? Wq : (mat == 1) ? Wk : (mat == 2) ? Wv : (mat == 3) ? We : Wsk;
    Wt5[mat * 16384 + c * 128 + k] = f2bf(W[k * 128 + c]);
}

// ---------------- shared GEMM pieces ----------------
#define LOAD_BFRAG(bfrag, Wt, wc, lane)                                         \
    _Pragma("unroll") for (int nt_ = 0; nt_ < 4; nt_++)                         \
    _Pragma("unroll") for (int kk_ = 0; kk_ < 4; kk_++) {                       \
        int col_ = (wc) + nt_ * 16 + ((lane) & 15);                             \
        int kidx_ = kk_ * 32 + ((lane) >> 4) * 8;                               \
        bfrag[nt_][kk_] = *(const s16x8*)&(Wt)[col_ * 128 + kidx_];             \
    }

// ---------------- kernel 1: node projections (single pass, all 4 mats) ----------------
__global__ __launch_bounds__(512, 1) void node_proj(
    const float* __restrict__ x, const short* __restrict__ Wt5,
    const float* __restrict__ bq, const float* __restrict__ bk,
    const float* __restrict__ bv, const float* __restrict__ bsk,
    short* __restrict__ qb, short* __restrict__ kb, short* __restrict__ vb,
    float* __restrict__ skb, int Nn) {
    __shared__ short Asm[TILE_M][136];
    int tid = threadIdx.x, wave = tid >> 6, lane = tid & 63;
    int row0 = blockIdx.x * TILE_M;

    for (int i_ = 0; i_ < 4; i_++) {
        int f_ = tid + i_ * 512;
        int r_ = f_ >> 5, c4_ = f_ & 31;
        int gr_ = row0 + r_;
        float4 v_ = (gr_ < Nn) ? ((const float4*)x)[(size_t)gr_ * 32 + c4_]
                               : make_float4(0.f, 0.f, 0.f, 0.f);
        short* d_ = &Asm[r_][c4_ * 4];
        d_[0] = f2bf(v_.x); d_[1] = f2bf(v_.y); d_[2] = f2bf(v_.z); d_[3] = f2bf(v_.w);
    }
    __syncthreads();

    int wr = (wave >> 1) * 16, wc = (wave & 1) * 64;

    for (int mat = 0; mat < 4; mat++) {
        const short* Wt = Wt5 + ((mat < 3) ? mat : 4) * 16384;
        const float* bias = (mat == 0) ? bq : (mat == 1) ? bk : (mat == 2) ? bv : bsk;
        s16x8 bfrag[4][4];
        LOAD_BFRAG(bfrag, Wt, wc, lane);
        f32x4 acc[4];
#pragma unroll
        for (int nt = 0; nt < 4; nt++) acc[nt] = (f32x4){0.f, 0.f, 0.f, 0.f};
#pragma unroll
        for (int kk = 0; kk < 4; kk++) {
            s16x8 a = *(const s16x8*)&Asm[wr + (lane & 15)][kk * 32 + (lane >> 4) * 8];
#pragma unroll
            for (int nt = 0; nt < 4; nt++)
                acc[nt] = __builtin_amdgcn_mfma_f32_16x16x32_bf16(a, bfrag[nt][kk], acc[nt], 0, 0, 0);
        }
#pragma unroll
        for (int nt = 0; nt < 4; nt++) {
            int col = wc + nt * 16 + (lane & 15);
            float b = bias[col];
#pragma unroll
            for (int i = 0; i < 4; i++) {
                int row = row0 + wr + (lane >> 4) * 4 + i;
                if (row < Nn) {
                    float val = acc[nt][i] + b;
                    if (mat == 0)      qb[(size_t)row * 128 + col] = f2bf(val);
                    else if (mat == 1) kb[(size_t)row * 128 + col] = f2bf(val);
                    else if (mat == 2) vb[(size_t)row * 128 + col] = f2bf(val);
                    else               skb[(size_t)row * 128 + col] = val;
                }
            }
        }
    }
}

// ---------------- CSR build ----------------
__global__ void hist_dst(const int* __restrict__ eidx, int* __restrict__ cnt, int Ee) {
    int e = blockIdx.x * 256 + threadIdx.x;
    if (e < Ee) atomicAdd(&cnt[eidx[Ee + e]], 1);
}

__global__ __launch_bounds__(1024, 1) void scan_rowptr(const int* __restrict__ cnt,
                                                       int* __restrict__ rowptr, int Nn) {
    __shared__ int part[1024];
    int t = threadIdx.x;
    int chunk = (Nn + 1023) / 1024;
    int b = t * chunk;
    int e = b + chunk; if (e > Nn) e = Nn;
    int sum = 0;
    for (int i = b; i < e && i < Nn; i++) sum += cnt[i];
    part[t] = sum;
    __syncthreads();
    for (int off = 1; off < 1024; off <<= 1) {
        int v = (t >= off) ? part[t - off] : 0;
        __syncthreads();
        part[t] += v;
        __syncthreads();
    }
    int run = part[t] - sum;   // exclusive
    for (int i = b; i < e && i < Nn; i++) { rowptr[i] = run; run += cnt[i]; }
    if (t == 1023) rowptr[Nn] = part[1023];
}

// writes perm + srcs/dsts materialized in perm (dst-sorted) order
__global__ void fill_perm2(const int* __restrict__ eidx, const int* __restrict__ rowptr,
                           int* __restrict__ cursor, int* __restrict__ perm,
                           int* __restrict__ srcs, int* __restrict__ dsts, int Ee) {
    int e = blockIdx.x * 256 + threadIdx.x;
    if (e >= Ee) return;
    int s = eidx[e];
    int d = eidx[Ee + e];
    int pos = atomicAdd(&cursor[d], 1);
    int i = rowptr[d] + pos;
    perm[i] = e; srcs[i] = s; dsts[i] = d;
}

// ---------------- kernel 2: fused edge kernel with LDS segment aggregation ----------------
// One 64-edge tile (dst-sorted) per block. Segments (runs of equal dst) are
// aggregated in LDS; interior dsts (full CSR range inside tile) get FINAL
// out written non-atomically; only boundary dsts use global atomics.
__global__ __launch_bounds__(512) void fused_edge(
    const float* __restrict__ ea, const short* __restrict__ Wt5,
    const short* __restrict__ qb, const short* __restrict__ kb,
    const short* __restrict__ vb,
    const int* __restrict__ perm, const int* __restrict__ srcs,
    const int* __restrict__ dsts, const int* __restrict__ rowptr,
    const float* __restrict__ skb, unsigned char* __restrict__ flags,
    float* __restrict__ outacc, float* __restrict__ denom,
    float* __restrict__ out, int Ee) {
    const short* Wt = Wt5 + 3 * 16384;  // We

    __shared__ short U[TILE_M][136];            // union: Asm (input), then Es (bf16 proj)
    __shared__ float Pls[TILE_M][HEADS];        // p = exp(alpha)
    __shared__ float segacc[SEGCAP][132];       // per-segment channel sums
    __shared__ float segaccD[SEGCAP][HEADS];    // per-segment denom sums
    __shared__ int Pe[TILE_M], Ss[TILE_M], Ds[TILE_M];
    __shared__ int segid[TILE_M];
    __shared__ int segdst[SEGCAP];
    __shared__ unsigned char segint[SEGCAP];
    __shared__ int nsegS;

    int tid = threadIdx.x, wave = tid >> 6, lane = tid & 63;
    int e0 = blockIdx.x * TILE_M;
    int cnt = Ee - e0; if (cnt > TILE_M) cnt = TILE_M;

    // ---- phase -1: ids + zero segment accumulators ----
    if (tid < TILE_M) {
        Pe[tid] = (tid < cnt) ? perm[e0 + tid] : 0;
        Ss[tid] = (tid < cnt) ? srcs[e0 + tid] : 0;
        Ds[tid] = (tid < cnt) ? dsts[e0 + tid] : -1;
    }
    for (int i = tid; i < SEGCAP * 132; i += 512) ((float*)segacc)[i] = 0.f;
    if (tid < SEGCAP * HEADS) ((float*)segaccD)[tid] = 0.f;
    __syncthreads();

    // ---- phase 0: stage ea -> U (perm via LDS; 512B-granular rows) ----
    for (int i_ = 0; i_ < 4; i_++) {
        int f_ = tid + i_ * 512;
        int r_ = f_ >> 5, c4_ = f_ & 31;
        float4 v_ = make_float4(0.f, 0.f, 0.f, 0.f);
        if (r_ < cnt) v_ = ((const float4*)ea)[(size_t)Pe[r_] * 32 + c4_];
        short* d_ = &U[r_][c4_ * 4];
        d_[0] = f2bf(v_.x); d_[1] = f2bf(v_.y); d_[2] = f2bf(v_.z); d_[3] = f2bf(v_.w);
    }
    __syncthreads();

    // ---- phase 1: MFMA e = ea_tile @ We (acc in regs) ----
    int wr = (wave >> 1) * 16, wc = (wave & 1) * 64;
    f32x4 acc[4];
    {
        s16x8 bfrag[4][4];
        LOAD_BFRAG(bfrag, Wt, wc, lane);    // L1-resident 32KB
#pragma unroll
        for (int nt = 0; nt < 4; nt++) acc[nt] = (f32x4){0.f, 0.f, 0.f, 0.f};
#pragma unroll
        for (int kk = 0; kk < 4; kk++) {
            s16x8 a = *(const s16x8*)&U[wr + (lane & 15)][kk * 32 + (lane >> 4) * 8];
#pragma unroll
            for (int nt = 0; nt < 4; nt++)
                acc[nt] = __builtin_amdgcn_mfma_f32_16x16x32_bf16(a, bfrag[nt][kk], acc[nt], 0, 0, 0);
        }
    }
    __syncthreads();   // all reads of U done

    // ---- phase 1b: write Es (bf16) over U ----
#pragma unroll
    for (int nt = 0; nt < 4; nt++) {
        int col = wc + nt * 16 + (lane & 15);
#pragma unroll
        for (int i = 0; i < 4; i++)
            U[wr + (lane >> 4) * 4 + i][col] = f2bf(acc[nt][i]);
    }
    __syncthreads();

    // ---- phase 2: alpha + exp (one (edge,head) per thread) + segment scan ----
    {
        int eL = tid >> 3, h = tid & 7;
        if (eL < cnt) {
            int src = Ss[eL], dst = Ds[eL];
            const short* qp = &qb[(size_t)dst * 128 + h * 16];
            const short* kp = &kb[(size_t)src * 128 + h * 16];
            s16x8 q0 = *(const s16x8*)qp, q1 = *(const s16x8*)(qp + 8);
            s16x8 k0 = *(const s16x8*)kp, k1 = *(const s16x8*)(kp + 8);
            s16x8 ev0 = *(const s16x8*)&U[eL][h * 16];
            s16x8 ev1 = *(const s16x8*)&U[eL][h * 16 + 8];
            float a_val = 0.f;
#pragma unroll
            for (int c = 0; c < 8; c++) {
                a_val += bf2f(q0[c]) * (bf2f(k0[c]) + bf2f(ev0[c]));
                a_val += bf2f(q1[c]) * (bf2f(k1[c]) + bf2f(ev1[c]));
            }
            a_val *= 0.25f;                  // 1/sqrt(C), C=16
            // exp WITHOUT per-node max (cancels in p/sum p); clamp for inf-safety
            Pls[eL][h] = __expf(fminf(a_val, 60.f));
        }
    }
    if (tid < TILE_M) {   // wave 0: segment scan over the tile
        int prev = (tid == 0) ? -2 : Ds[tid - 1];
        bool b = (tid < cnt) && (tid == 0 || Ds[tid] != prev);
        unsigned long long mask = __ballot(b);
        int sid = (int)__popcll(mask & ((2ull << tid) - 1ull)) - 1;
        segid[tid] = sid;
        if (b && sid < SEGCAP) {
            int d = Ds[tid];
            segdst[sid] = d;
            int rb = rowptr[d], re = rowptr[d + 1];
            segint[sid] = (rb >= e0 && re <= e0 + cnt) ? 1 : 0;
        }
        if (tid == 0) nsegS = (int)__popcll(mask);
    }
    __syncthreads();

    int nseg = nsegS;
    bool ovf = (nseg > SEGCAP);

    // ---- phase 3: PV — 2 edges per wave-iteration, register segment aggregation ----
    {
        int half = lane >> 5, li = lane & 31, h = li >> 2;  // 4 channels per lane
        int base = wave * 8;
        float c0 = 0.f, c1 = 0.f, c2 = 0.f, c3 = 0.f, pd = 0.f;
        int curs = -1, curd = -1;
#pragma unroll
        for (int k = 0; k < 4; k++) {
            int eL = base + 2 * k + half;
            if (eL >= cnt) continue;
            int sg = segid[eL];
            if (sg != curs) {
                if (curs >= 0) {
                    if (!ovf) {
                        atomicAdd(&segacc[curs][li * 4 + 0], c0);
                        atomicAdd(&segacc[curs][li * 4 + 1], c1);
                        atomicAdd(&segacc[curs][li * 4 + 2], c2);
                        atomicAdd(&segacc[curs][li * 4 + 3], c3);
                        if ((li & 3) == 0) atomicAdd(&segaccD[curs][h], pd);
                    } else {
                        atomicAdd(&outacc[(size_t)curd * 128 + li * 4 + 0], c0);
                        atomicAdd(&outacc[(size_t)curd * 128 + li * 4 + 1], c1);
                        atomicAdd(&outacc[(size_t)curd * 128 + li * 4 + 2], c2);
                        atomicAdd(&outacc[(size_t)curd * 128 + li * 4 + 3], c3);
                        if ((li & 3) == 0) atomicAdd(&denom[(size_t)curd * HEADS + h], pd);
                    }
                }
                c0 = c1 = c2 = c3 = pd = 0.f;
                curs = sg; curd = Ds[eL];
            }
            float p = Pls[eL][h];                                   // LDS broadcast
            int src = Ss[eL];
            uint2 vv = *(const uint2*)&vb[(size_t)src * 128 + li * 4];
            uint2 ee = *(const uint2*)&U[eL][li * 4];
            c0 += p * (bf2f((short)(vv.x & 0xffff)) + bf2f((short)(ee.x & 0xffff)));
            c1 += p * (bf2f((short)(vv.x >> 16))    + bf2f((short)(ee.x >> 16)));
            c2 += p * (bf2f((short)(vv.y & 0xffff)) + bf2f((short)(ee.y & 0xffff)));
            c3 += p * (bf2f((short)(vv.y >> 16))    + bf2f((short)(ee.y >> 16)));
            if ((li & 3) == 0) pd += p;
        }
        if (curs >= 0) {
            if (!ovf) {
                atomicAdd(&segacc[curs][li * 4 + 0], c0);
                atomicAdd(&segacc[curs][li * 4 + 1], c1);
                atomicAdd(&segacc[curs][li * 4 + 2], c2);
                atomicAdd(&segacc[curs][li * 4 + 3], c3);
                if ((li & 3) == 0) atomicAdd(&segaccD[curs][h], pd);
            } else {
                atomicAdd(&outacc[(size_t)curd * 128 + li * 4 + 0], c0);
                atomicAdd(&outacc[(size_t)curd * 128 + li * 4 + 1], c1);
                atomicAdd(&outacc[(size_t)curd * 128 + li * 4 + 2], c2);
                atomicAdd(&outacc[(size_t)curd * 128 + li * 4 + 3], c3);
                if ((li & 3) == 0) atomicAdd(&denom[(size_t)curd * HEADS + h], pd);
            }
        }
    }
    __syncthreads();

    // ---- phase 4: resolve segments ----
    if (ovf) {
        if (tid < cnt) flags[Ds[tid]] = 1;   // finalize will handle these dsts
    } else {
        for (int idx = tid; idx < SEGCAP * 128; idx += 512) {
            int sg = idx >> 7, ch = idx & 127;
            if (sg < nseg) {
                int d = segdst[sg];
                float val = segacc[sg][ch];
                float dn = segaccD[sg][ch >> 4];
                if (segint[sg]) {
                    out[(size_t)d * 128 + ch] = val / (dn + 1e-16f) + skb[(size_t)d * 128 + ch];
                } else {
                    atomicAdd(&outacc[(size_t)d * 128 + ch], val);
                    if ((ch & 15) == 0) atomicAdd(&denom[(size_t)d * HEADS + (ch >> 4)], dn);
                }
            }
        }
    }
}

// ---------------- kernel 3: finalize boundary / flagged / deg-0 nodes ----------------
__global__ void finalize(const float* __restrict__ outacc, const float* __restrict__ denom,
                         const float* __restrict__ skb, const int* __restrict__ rowptr,
                         const unsigned char* __restrict__ flags,
                         float* __restrict__ out, int total4) {
    int idx = blockIdx.x * 256 + threadIdx.x;
    if (idx >= total4) return;                 // total4 = N*32 (float4 units)
    int n = idx >> 5, q4 = idx & 31;
    int rb = rowptr[n], re = rowptr[n + 1];
    bool proc = (re == rb) || flags[n] || ((rb >> 6) != ((re - 1) >> 6));
    if (!proc) return;                         // interior: fused_edge already wrote out
    int h = q4 >> 2;
    float inv = 1.f / (denom[(size_t)n * HEADS + h] + 1e-16f);
    float4 a = ((const float4*)outacc)[idx];
    float4 sk = ((const float4*)skb)[idx];
    float4 r = make_float4(a.x * inv + sk.x, a.y * inv + sk.y,
                           a.z * inv + sk.z, a.w * inv + sk.w);
    ((float4*)out)[idx] = r;
}

// ---------------- launch ----------------
extern "C" void kernel_launch(void* const* d_in, const int* in_sizes, int n_in,
                              void* d_out, int out_size, void* d_ws, size_t ws_size,
                              hipStream_t stream) {
    const float* x   = (const float*)d_in[0];
    const float* ea  = (const float*)d_in[1];
    const float* Wq  = (const float*)d_in[2];
    const float* bq  = (const float*)d_in[3];
    const float* Wk  = (const float*)d_in[4];
    const float* bk  = (const float*)d_in[5];
    const float* Wv  = (const float*)d_in[6];
    const float* bv  = (const float*)d_in[7];
    const float* We  = (const float*)d_in[8];
    const float* Wsk = (const float*)d_in[9];
    const float* bsk = (const float*)d_in[10];
    const int*   eidx = (const int*)d_in[11];

    int Nn = in_sizes[0] / 128;   // 50000
    int Ee = in_sizes[1] / 128;   // 800000
    float* out = (float*)d_out;

    // ws layout
    size_t need = 0;
    size_t off_qb  = need; need += (size_t)Nn * 128 * 2;   // qb bf16
    size_t off_kb  = need; need += (size_t)Nn * 128 * 2;   // kb bf16
    size_t off_vb  = need; need += (size_t)Nn * 128 * 2;   // vb bf16
    size_t off_skb = need; need += (size_t)Nn * 128 * 4;   // skip f32
    size_t off_oa  = need; need += (size_t)Nn * 128 * 4;   // outacc f32
    size_t off_dn  = need; need += (size_t)Nn * HEADS * 4; // denom f32
    size_t off_perm= need; need += (size_t)Ee * 4;         // perm
    size_t off_src = need; need += (size_t)Ee * 4;         // srcs (perm order)
    size_t off_dst = need; need += (size_t)Ee * 4;         // dsts (perm order)
    size_t off_rp  = need; need += (size_t)(Nn + 1) * 4;   // rowptr
    size_t off_cnt = need; need += (size_t)Nn * 4;         // counts
    size_t off_cur = need; need += (size_t)Nn * 4;         // cursors
    size_t off_wt  = need; need += 5 * 16384 * 2;          // Wt5
    size_t off_fl  = need; need += (size_t)Nn;             // flags (bytes)
    (void)need;

    char* ws = (char*)d_ws;
    short* qb    = (short*)(ws + off_qb);
    short* kb    = (short*)(ws + off_kb);
    short* vb    = (short*)(ws + off_vb);
    float* skb   = (float*)(ws + off_skb);
    float* outacc= (float*)(ws + off_oa);
    float* denom = (float*)(ws + off_dn);
    int*   perm  = (int*)(ws + off_perm);
    int*   srcs  = (int*)(ws + off_src);
    int*   dsts  = (int*)(ws + off_dst);
    int*   rowptr= (int*)(ws + off_rp);
    int*   cnt   = (int*)(ws + off_cnt);
    int*   cursor= (int*)(ws + off_cur);
    short* Wt5   = (short*)(ws + off_wt);
    unsigned char* flags = (unsigned char*)(ws + off_fl);

    hipMemsetAsync(cnt, 0, (size_t)Nn * 4, stream);
    hipMemsetAsync(cursor, 0, (size_t)Nn * 4, stream);
    hipMemsetAsync(outacc, 0, (size_t)Nn * 128 * 4, stream);
    hipMemsetAsync(denom, 0, (size_t)Nn * HEADS * 4, stream);
    hipMemsetAsync(flags, 0, (size_t)Nn, stream);

    prep_w<<<(5 * 16384 + 255) / 256, 256, 0, stream>>>(Wq, Wk, Wv, We, Wsk, Wt5);
    hist_dst<<<(Ee + 255) / 256, 256, 0, stream>>>(eidx, cnt, Ee);
    scan_rowptr<<<1, 1024, 0, stream>>>(cnt, rowptr, Nn);
    fill_perm2<<<(Ee + 255) / 256, 256, 0, stream>>>(eidx, rowptr, cursor, perm, srcs, dsts, Ee);
    node_proj<<<(Nn + TILE_M - 1) / TILE_M, 512, 0, stream>>>(
        x, Wt5, bq, bk, bv, bsk, qb, kb, vb, skb, Nn);
    fused_edge<<<(Ee + TILE_M - 1) / TILE_M, 512, 0, stream>>>(
        ea, Wt5, qb, kb, vb, perm, srcs, dsts, rowptr, skb, flags,
        outacc, denom, out, Ee);
    finalize<<<(Nn * 32 + 255) / 256, 256, 0, stream>>>(
        outacc, denom, skb, rowptr, flags, out, Nn * 32);
}